// Round 20
// baseline (200.830 us; speedup 1.0000x reference)
//
#include <hip/hip_runtime.h>
#include <hip/hip_bf16.h>

typedef unsigned short u16;
typedef unsigned int u32;
typedef __attribute__((ext_vector_type(8))) short bf16x8;
typedef __attribute__((ext_vector_type(4))) float f32x4;
typedef __attribute__((ext_vector_type(16))) float f32x16;

#define AS1(p) ((const __attribute__((address_space(1))) void*)(p))
#define AS3(p) ((__attribute__((address_space(3))) void*)(p))
#define STG(src, dst) __builtin_amdgcn_global_load_lds(AS1(src), AS3(dst), 16, 0, 0)

#if __has_builtin(__builtin_amdgcn_exp2f)
#define EXP2F(x) __builtin_amdgcn_exp2f(x)
#else
#define EXP2F(x) exp2f(x)
#endif

// vt interleaved layout: [bh][n>>2][64 dd][n&3]; per-bh stride = 2048*64 = 131072 u16.
#define VT_BH_STRIDE 131072

static __device__ __forceinline__ float b2f(u16 u) {
  union { unsigned int i; float f; } v; v.i = ((unsigned int)u) << 16; return v.f;
}
static __device__ __forceinline__ u16 f2b(float f) {
  union { float f; unsigned int i; } v; v.f = f;
  unsigned int r = v.i + 0x7FFFu + ((v.i >> 16) & 1u);
  return (u16)(r >> 16);
}
static __device__ __forceinline__ u32 cvt_pk_bf16(float lo, float hi) {
  u32 r;
  asm("v_cvt_pk_bf16_f32 %0, %1, %2" : "=v"(r) : "v"(lo), "v"(hi));
  return r;
}
static __device__ __forceinline__ void permswap(u32& a, u32& b) {
  asm("v_permlane32_swap_b32 %0, %1" : "+v"(a), "+v"(b));
}

// ---------------- fused prep: x cast (blocks 0..2047) + Wqkv^T (2048..5119) + Wproj^T (5120..6143) ----------------
__global__ __launch_bounds__(256) void prep(const float* __restrict__ x, u16* __restrict__ xb,
                                            const float* __restrict__ Wqkv, u16* __restrict__ wqkvT,
                                            const float* __restrict__ Wproj, u16* __restrict__ wprojT) {
  __shared__ float tile[32][33];
  const int bid = blockIdx.x, t = threadIdx.x;
  if (bid < 2048) {
    const int n8 = 8192 * 1024 / 8;
    for (int i = bid * 256 + t; i < n8; i += 2048 * 256) {
      const float4* s = (const float4*)(x + (size_t)i * 8);
      float4 a = s[0], b = s[1];
      bf16x8 o;
      o[0] = (short)f2b(a.x); o[1] = (short)f2b(a.y); o[2] = (short)f2b(a.z); o[3] = (short)f2b(a.w);
      o[4] = (short)f2b(b.x); o[5] = (short)f2b(b.y); o[6] = (short)f2b(b.z); o[7] = (short)f2b(b.w);
      *(bf16x8*)(xb + (size_t)i * 8) = o;
    }
  } else {
    const float* src; u16* dst; int R, C, cx, ry;
    if (bid < 5120) { const int l = bid - 2048; src = Wqkv; dst = wqkvT; R = 1024; C = 3072; cx = l % 96; ry = l / 96; }
    else            { const int l = bid - 5120; src = Wproj; dst = wprojT; R = 1024; C = 1024; cx = l & 31; ry = l >> 5; }
    const int c0 = cx * 32, r0 = ry * 32;
    const int tx = t & 31, ty = t >> 5;
    for (int i = ty; i < 32; i += 8) tile[i][tx] = src[(size_t)(r0 + i) * C + c0 + tx];
    __syncthreads();
    for (int i = ty; i < 32; i += 8) dst[(size_t)(c0 + i) * R + r0 + tx] = f2b(tile[tx][i]);
  }
}

// ---------------- m97-structure bf16 GEMM + fused V-transpose; 1D grid w/ XCD-chunked swizzle ----------------
// Grid = nm*nn blocks (both grids %8==0). swz = (id&7)*cpx + id>>3 is bijective; decode
// ni = swz/nm (slow) so each XCD holds a narrow band of B-panels in its L2 and streams
// the shared A through L3.
template <typename OutT, bool WVT>
__global__ __launch_bounds__(256) void gemm_bt_bias(
    const u16* __restrict__ A,     // [M][K] bf16
    const u16* __restrict__ BT,    // [N][K] bf16 (K contiguous)
    const float* __restrict__ bias,// [N] fp32
    OutT* __restrict__ C,          // [M][N]
    int M, int N, int K, int nm,
    u16* __restrict__ vt) {        // [B*H][512][64][4] interleaved (WVT only)
  __shared__ alignas(16) u16 Als[128 * 32];
  __shared__ alignas(16) u16 Bls[128 * 32];
  const int nwg = gridDim.x, cpx = nwg >> 3, id0 = blockIdx.x;
  const int swz = (id0 & 7) * cpx + (id0 >> 3);
  const int mi = swz % nm, ni = swz / nm;
  const int m0 = mi * 128, n0 = ni * 128;
  const int t = threadIdx.x;
  const int w = t >> 6, lane = t & 63;
  const int wr = w >> 1, wc = w & 1;
  const int rlo = lane & 15, g = lane >> 4;

  f32x4 acc[4][4] = {};

  const int r0 = t >> 2;
  const int c0 = (t & 3) << 3;
  const u16* aSrc = A + (size_t)(m0 + r0) * K + c0;
  const u16* bSrc = BT + (size_t)(n0 + r0) * K + c0;

  for (int k0 = 0; k0 < K; k0 += 32) {
    __builtin_amdgcn_global_load_lds(AS1(aSrc + k0), AS3(&Als[t * 8]), 16, 0, 0);
    __builtin_amdgcn_global_load_lds(AS1(aSrc + (size_t)64 * K + k0), AS3(&Als[(t + 256) * 8]), 16, 0, 0);
    __builtin_amdgcn_global_load_lds(AS1(bSrc + k0), AS3(&Bls[t * 8]), 16, 0, 0);
    __builtin_amdgcn_global_load_lds(AS1(bSrc + (size_t)64 * K + k0), AS3(&Bls[(t + 256) * 8]), 16, 0, 0);
    __syncthreads();

    bf16x8 a[4], b[4];
    #pragma unroll
    for (int m = 0; m < 4; ++m)
      a[m] = *(const bf16x8*)&Als[(wr * 64 + m * 16 + rlo) * 32 + g * 8];
    #pragma unroll
    for (int n = 0; n < 4; ++n)
      b[n] = *(const bf16x8*)&Bls[(wc * 64 + n * 16 + rlo) * 32 + g * 8];
    #pragma unroll
    for (int m = 0; m < 4; ++m)
      #pragma unroll
      for (int n = 0; n < 4; ++n)
        acc[m][n] = __builtin_amdgcn_mfma_f32_16x16x32_bf16(a[m], b[n], acc[m][n], 0, 0, 0);
    __syncthreads();
  }

  #pragma unroll
  for (int n = 0; n < 4; ++n) {
    const int col = n0 + wc * 64 + n * 16 + rlo;
    const float bv = bias[col];
    #pragma unroll
    for (int m = 0; m < 4; ++m) {
      const int row = m0 + wr * 64 + m * 16 + g * 4;
      u16 tmp[4];
      #pragma unroll
      for (int i = 0; i < 4; ++i) {
        float r = acc[m][n][i] + bv;
        if constexpr (sizeof(OutT) == 2) {
          const u16 hv = f2b(r);
          C[(size_t)(row + i) * N + col] = (OutT)hv;
          if constexpr (WVT) tmp[i] = hv;
        } else {
          C[(size_t)(row + i) * N + col] = (OutT)r;
        }
      }
      if constexpr (WVT) {
        if (col >= 2048) {
          const int cv = col - 2048;
          const int h = cv >> 6, dd = cv & 63;
          const int b = row >> 11, nloc = row & 2047;  // tile never crosses a batch boundary
          uint2 pv;
          pv.x = (u32)tmp[0] | ((u32)tmp[1] << 16);
          pv.y = (u32)tmp[2] | ((u32)tmp[3] << 16);
          *(uint2*)&vt[(size_t)(b * 16 + h) * VT_BH_STRIDE + (nloc >> 2) * 256 + dd * 4] = pv;
        }
      }
    }
  }
}

// ---------------- causal flash attention: (q-half x kv-subtile) wave split + DBUF staging (r18 best) ----------------
__global__ __launch_bounds__(256, 2) void attn_fwd(
    const u16* __restrict__ qkv,  // [B*N][3072] bf16; Q col 0, K col 1024
    const u16* __restrict__ VT,   // [B*H][512][64][4] bf16 interleaved
    u16* __restrict__ O) {        // [B*N][1024] bf16
  const int N = 2048, TD = 3072, D = 1024;
  const int bid = blockIdx.x;
  const int qp = bid >> 6, bh = bid & 63;
  const int b = bh >> 4, h = bh & 15;
  const int t = threadIdx.x, w = t >> 6, lane = t & 63;
  const int l31 = lane & 31, hi = lane >> 5;
  const int qh = w >> 1, st = w & 1;

  __shared__ alignas(16) u16 pool16[2][2][64 * 64];
  __shared__ float rsLds[2][32];
  float* poolf = (float*)&pool16[0][0][0];

  const int c1 = t, c2 = t + 256;
  const int r1 = c1 >> 3, sc1 = ((c1 & 7) ^ (r1 & 7)) * 8;
  const int r2 = c2 >> 3, sc2 = ((c2 & 7) ^ (r2 & 7)) * 8;
  const u16* kbase = qkv + (size_t)(b * N) * TD + D + h * 64;
  const u16* vbase = VT + (size_t)bh * VT_BH_STRIDE;

#define ASTAGE(buf, j0) do { \
    STG(kbase + (size_t)((j0) + r1) * TD + sc1, &pool16[buf][0][c1 * 8]); \
    STG(kbase + (size_t)((j0) + r2) * TD + sc2, &pool16[buf][0][c2 * 8]); \
    STG(vbase + (size_t)(j0) * 64 + c1 * 8, &pool16[buf][1][c1 * 8]); \
    STG(vbase + (size_t)(j0) * 64 + c2 * 8, &pool16[buf][1][c2 * 8]); } while (0)

  const float L2E = 1.44269504089f;
  const float NSH = -23.0830992f;  // -16*log2(e): p = exp2(s*L2E + NSH) = exp(s-16)

  for (int pass = 0; pass < 2; ++pass) {
    const int qt = pass ? (15 - qp) : qp;
    const int qbw = qt * 128 + qh * 64;

    bf16x8 qf[2][4];
    #pragma unroll
    for (int qs = 0; qs < 2; ++qs) {
      const u16* qp_ = qkv + ((size_t)(b * N) + qbw + qs * 32 + l31) * TD + h * 64 + hi * 8;
      #pragma unroll
      for (int c = 0; c < 4; ++c) {
        bf16x8 v = *(const bf16x8*)(qp_ + c * 16);
        #pragma unroll
        for (int j = 0; j < 8; ++j)
          v[j] = (short)f2b(b2f((u16)v[j]) * 0.125f);
        qf[qs][c] = v;
      }
    }

    f32x16 o_acc[2][2] = {};
    float psum[2] = {0.f, 0.f};
    const int jend = qt * 128 + 64;

    ASTAGE(0, 0);
    __syncthreads();

    int cur = 0;
    for (int j0 = 0; j0 <= jend; j0 += 64) {
      if (j0 + 64 <= jend) ASTAGE(cur ^ 1, j0 + 64);

      const int sb2 = j0 + st * 32;
      if (sb2 <= qbw + 63) {
        bf16x8 kf[4];
        {
          const int row = st * 32 + l31, sw = (row & 7) << 3;
          #pragma unroll
          for (int c = 0; c < 4; ++c)
            kf[c] = *(const bf16x8*)&pool16[cur][0][row * 64 + ((c * 16 + hi * 8) ^ sw)];
        }
        // vf: interleaved LDS [n>>2][64 dd][n&3]; 8 consecutive n = two uint2s (+0, +256)
        bf16x8 vf[2][2];  // [kc][dt]
        #pragma unroll
        for (int dt = 0; dt < 2; ++dt) {
          const int dd = dt * 32 + l31;
          #pragma unroll
          for (int kc = 0; kc < 2; ++kc) {
            const int nb = st * 32 + kc * 16 + hi * 8;
            union { uint2 q[2]; bf16x8 v; } u;
            u.q[0] = *(const uint2*)&pool16[cur][1][(nb >> 2) * 256 + dd * 4];
            u.q[1] = *(const uint2*)&pool16[cur][1][(nb >> 2) * 256 + 256 + dd * 4];
            vf[kc][dt] = u.v;
          }
        }

        #pragma unroll
        for (int qs = 0; qs < 2; ++qs) {
          if (qs == 0 && sb2 > qbw + 31) continue;
          const int qr = qbw + qs * 32 + l31;
          f32x16 S = {};
          __builtin_amdgcn_s_setprio(1);
          #pragma unroll
          for (int c = 0; c < 4; ++c)
            S = __builtin_amdgcn_mfma_f32_32x32x16_bf16(kf[c], qf[qs][c], S, 0, 0, 0);
          __builtin_amdgcn_s_setprio(0);
          if (sb2 + 31 > qbw + qs * 32) {
            const int kvb = sb2 + 4 * hi;
            #pragma unroll
            for (int r = 0; r < 16; ++r)
              if (kvb + (r & 3) + 8 * (r >> 2) > qr) S[r] = -1e30f;
          }
          float p[16];
          #pragma unroll
          for (int r = 0; r < 16; ++r) p[r] = EXP2F(fmaf(S[r], L2E, NSH));
          float ps = 0.f;
          #pragma unroll
          for (int r = 0; r < 16; ++r) ps += p[r];
          psum[qs] += ps;
          u32 wq[8];
          #pragma unroll
          for (int i = 0; i < 8; ++i) wq[i] = cvt_pk_bf16(p[2 * i], p[2 * i + 1]);
          permswap(wq[0], wq[2]); permswap(wq[1], wq[3]);
          permswap(wq[4], wq[6]); permswap(wq[5], wq[7]);
          union { u32 u[4]; bf16x8 v; } pa0, pa1;
          pa0.u[0] = wq[0]; pa0.u[1] = wq[1]; pa0.u[2] = wq[2]; pa0.u[3] = wq[3];
          pa1.u[0] = wq[4]; pa1.u[1] = wq[5]; pa1.u[2] = wq[6]; pa1.u[3] = wq[7];
          __builtin_amdgcn_s_setprio(1);
          #pragma unroll
          for (int dt = 0; dt < 2; ++dt) {
            o_acc[qs][dt] = __builtin_amdgcn_mfma_f32_32x32x16_bf16(pa0.v, vf[0][dt], o_acc[qs][dt], 0, 0, 0);
            o_acc[qs][dt] = __builtin_amdgcn_mfma_f32_32x32x16_bf16(pa1.v, vf[1][dt], o_acc[qs][dt], 0, 0, 0);
          }
          __builtin_amdgcn_s_setprio(0);
        }
      }
      __syncthreads();
      cur ^= 1;
    }

    float rsown[2];
    #pragma unroll
    for (int qs = 0; qs < 2; ++qs)
      rsown[qs] = psum[qs] + __shfl_xor(psum[qs], 32, 64);

    #pragma unroll
    for (int qs = 0; qs < 2; ++qs) {
      if (st != qs) {
        #pragma unroll
        for (int dt = 0; dt < 2; ++dt)
          #pragma unroll
          for (int r = 0; r < 16; ++r)
            poolf[qh * 2048 + (dt * 16 + r) * 64 + lane] = o_acc[qs][dt][r];
        rsLds[qh][l31] = rsown[qs];
      }
      __syncthreads();
      if (st == qs) {
        const float inv = 1.0f / (rsown[qs] + rsLds[qh][l31]);
        #pragma unroll
        for (int r = 0; r < 16; ++r) {
          const int qrow = (r & 3) + 8 * (r >> 2) + 4 * hi;
          const float invq = __shfl(inv, qrow, 64);
          const int q = qbw + qs * 32 + qrow;
          #pragma unroll
          for (int dt = 0; dt < 2; ++dt) {
            const float val = o_acc[qs][dt][r] + poolf[qh * 2048 + (dt * 16 + r) * 64 + lane];
            O[((size_t)(b * N) + q) * D + h * 64 + dt * 32 + l31] = f2b(val * invq);
          }
        }
      }
      __syncthreads();
    }
  }
#undef ASTAGE
}

extern "C" void kernel_launch(void* const* d_in, const int* in_sizes, int n_in,
                              void* d_out, int out_size, void* d_ws, size_t ws_size,
                              hipStream_t stream) {
  const float* x     = (const float*)d_in[0];
  // d_in[1] = causal_mask (fp32): handled structurally, unused
  const float* Wqkv  = (const float*)d_in[2];
  const float* bqkv  = (const float*)d_in[3];
  const float* Wproj = (const float*)d_in[4];
  const float* bproj = (const float*)d_in[5];
  float* out = (float*)d_out;

  const int B = 4, N = 2048, D = 1024, H = 16;
  const int BN = B * N;    // 8192
  const int TD = 3 * D;    // 3072

  char* ws = (char*)d_ws;
  u16* qkv    = (u16*)(ws);                      // 50,331,648 B
  u16* vt     = (u16*)(ws + 50331648);           // 16,777,216 B
  u16* aout   = (u16*)(ws + 67108864);           // 16,777,216 B
  u16* wqkvT  = (u16*)(ws + 83886080);           //  6,291,456 B
  u16* wprojT = (u16*)(ws + 90177536);           //  2,097,152 B
  u16* xb     = (u16*)(ws + 92274688);           // 16,777,216 B

  // 1) fused prep: x->bf16 cast + both weight transposes
  prep<<<6144, 256, 0, stream>>>(x, xb, Wqkv, wqkvT, Wproj, wprojT);
  // 2) QKV projection (r9 structure, XCD-chunked swizzle) + fused V-transpose
  gemm_bt_bias<u16, true><<<1536, 256, 0, stream>>>(xb, wqkvT, bqkv, qkv, BN, TD, D, 64, vt);
  // 3) causal flash attention (r18 best: 128-row paired q-tiles, 8 qp x 64 bh)
  attn_fwd<<<512, 256, 0, stream>>>(qkv, vt, aout);
  // 4) output projection (fp32 out + bias, XCD-chunked swizzle)
  gemm_bt_bias<float, false><<<512, 256, 0, stream>>>(aout, wprojT, bproj, out, BN, D, D, 64, nullptr);
}

// Round 21
// 179.347 us; speedup vs baseline: 1.1198x; 1.1198x over previous
//
#include <hip/hip_runtime.h>
#include <hip/hip_bf16.h>

typedef unsigned short u16;
typedef unsigned int u32;
typedef __attribute__((ext_vector_type(8))) short bf16x8;
typedef __attribute__((ext_vector_type(4))) float f32x4;
typedef __attribute__((ext_vector_type(16))) float f32x16;

#define AS1(p) ((const __attribute__((address_space(1))) void*)(p))
#define AS3(p) ((__attribute__((address_space(3))) void*)(p))
#define STG(src, dst) __builtin_amdgcn_global_load_lds(AS1(src), AS3(dst), 16, 0, 0)

#if __has_builtin(__builtin_amdgcn_exp2f)
#define EXP2F(x) __builtin_amdgcn_exp2f(x)
#else
#define EXP2F(x) exp2f(x)
#endif

// vt interleaved layout: [bh][n>>2][64 dd][n&3]; per-bh stride = 2048*64 = 131072 u16.
#define VT_BH_STRIDE 131072

static __device__ __forceinline__ float b2f(u16 u) {
  union { unsigned int i; float f; } v; v.i = ((unsigned int)u) << 16; return v.f;
}
static __device__ __forceinline__ u16 f2b(float f) {
  union { float f; unsigned int i; } v; v.f = f;
  unsigned int r = v.i + 0x7FFFu + ((v.i >> 16) & 1u);
  return (u16)(r >> 16);
}
static __device__ __forceinline__ u32 cvt_pk_bf16(float lo, float hi) {
  u32 r;
  asm("v_cvt_pk_bf16_f32 %0, %1, %2" : "=v"(r) : "v"(lo), "v"(hi));
  return r;
}
static __device__ __forceinline__ void permswap(u32& a, u32& b) {
  asm("v_permlane32_swap_b32 %0, %1" : "+v"(a), "+v"(b));
}

// ---------------- fused prep: x cast (blocks 0..2047) + Wqkv^T (2048..5119) + Wproj^T (5120..6143) ----------------
__global__ __launch_bounds__(256) void prep(const float* __restrict__ x, u16* __restrict__ xb,
                                            const float* __restrict__ Wqkv, u16* __restrict__ wqkvT,
                                            const float* __restrict__ Wproj, u16* __restrict__ wprojT) {
  __shared__ float tile[32][33];
  const int bid = blockIdx.x, t = threadIdx.x;
  if (bid < 2048) {
    const int n8 = 8192 * 1024 / 8;
    for (int i = bid * 256 + t; i < n8; i += 2048 * 256) {
      const float4* s = (const float4*)(x + (size_t)i * 8);
      float4 a = s[0], b = s[1];
      bf16x8 o;
      o[0] = (short)f2b(a.x); o[1] = (short)f2b(a.y); o[2] = (short)f2b(a.z); o[3] = (short)f2b(a.w);
      o[4] = (short)f2b(b.x); o[5] = (short)f2b(b.y); o[6] = (short)f2b(b.z); o[7] = (short)f2b(b.w);
      *(bf16x8*)(xb + (size_t)i * 8) = o;
    }
  } else {
    const float* src; u16* dst; int R, C, cx, ry;
    if (bid < 5120) { const int l = bid - 2048; src = Wqkv; dst = wqkvT; R = 1024; C = 3072; cx = l % 96; ry = l / 96; }
    else            { const int l = bid - 5120; src = Wproj; dst = wprojT; R = 1024; C = 1024; cx = l & 31; ry = l >> 5; }
    const int c0 = cx * 32, r0 = ry * 32;
    const int tx = t & 31, ty = t >> 5;
    for (int i = ty; i < 32; i += 8) tile[i][tx] = src[(size_t)(r0 + i) * C + c0 + tx];
    __syncthreads();
    for (int i = ty; i < 32; i += 8) dst[(size_t)(c0 + i) * R + r0 + tx] = f2b(tile[tx][i]);
  }
}

// ---------------- m97-structure bf16 GEMM (r9 measured best) + fused V-transpose (interleaved vt) ----------------
template <typename OutT, bool WVT>
__global__ __launch_bounds__(256) void gemm_bt_bias(
    const u16* __restrict__ A,     // [M][K] bf16
    const u16* __restrict__ BT,    // [N][K] bf16 (K contiguous)
    const float* __restrict__ bias,// [N] fp32
    OutT* __restrict__ C,          // [M][N]
    int M, int N, int K,
    u16* __restrict__ vt) {        // [B*H][512][64][4] interleaved (WVT only)
  __shared__ alignas(16) u16 Als[128 * 32];
  __shared__ alignas(16) u16 Bls[128 * 32];
  const int m0 = blockIdx.x * 128, n0 = blockIdx.y * 128;
  const int t = threadIdx.x;
  const int w = t >> 6, lane = t & 63;
  const int wr = w >> 1, wc = w & 1;
  const int rlo = lane & 15, g = lane >> 4;

  f32x4 acc[4][4] = {};

  const int r0 = t >> 2;
  const int c0 = (t & 3) << 3;
  const u16* aSrc = A + (size_t)(m0 + r0) * K + c0;
  const u16* bSrc = BT + (size_t)(n0 + r0) * K + c0;

  for (int k0 = 0; k0 < K; k0 += 32) {
    __builtin_amdgcn_global_load_lds(AS1(aSrc + k0), AS3(&Als[t * 8]), 16, 0, 0);
    __builtin_amdgcn_global_load_lds(AS1(aSrc + (size_t)64 * K + k0), AS3(&Als[(t + 256) * 8]), 16, 0, 0);
    __builtin_amdgcn_global_load_lds(AS1(bSrc + k0), AS3(&Bls[t * 8]), 16, 0, 0);
    __builtin_amdgcn_global_load_lds(AS1(bSrc + (size_t)64 * K + k0), AS3(&Bls[(t + 256) * 8]), 16, 0, 0);
    __syncthreads();

    bf16x8 a[4], b[4];
    #pragma unroll
    for (int m = 0; m < 4; ++m)
      a[m] = *(const bf16x8*)&Als[(wr * 64 + m * 16 + rlo) * 32 + g * 8];
    #pragma unroll
    for (int n = 0; n < 4; ++n)
      b[n] = *(const bf16x8*)&Bls[(wc * 64 + n * 16 + rlo) * 32 + g * 8];
    #pragma unroll
    for (int m = 0; m < 4; ++m)
      #pragma unroll
      for (int n = 0; n < 4; ++n)
        acc[m][n] = __builtin_amdgcn_mfma_f32_16x16x32_bf16(a[m], b[n], acc[m][n], 0, 0, 0);
    __syncthreads();
  }

  #pragma unroll
  for (int n = 0; n < 4; ++n) {
    const int col = n0 + wc * 64 + n * 16 + rlo;
    const float bv = bias[col];
    #pragma unroll
    for (int m = 0; m < 4; ++m) {
      const int row = m0 + wr * 64 + m * 16 + g * 4;
      u16 tmp[4];
      #pragma unroll
      for (int i = 0; i < 4; ++i) {
        float r = acc[m][n][i] + bv;
        if constexpr (sizeof(OutT) == 2) {
          const u16 hv = f2b(r);
          C[(size_t)(row + i) * N + col] = (OutT)hv;
          if constexpr (WVT) tmp[i] = hv;
        } else {
          C[(size_t)(row + i) * N + col] = (OutT)r;
        }
      }
      if constexpr (WVT) {
        if (col >= 2048) {
          const int cv = col - 2048;
          const int h = cv >> 6, dd = cv & 63;
          const int b = row >> 11, nloc = row & 2047;  // tile never crosses a batch boundary
          uint2 pv;
          pv.x = (u32)tmp[0] | ((u32)tmp[1] << 16);
          pv.y = (u32)tmp[2] | ((u32)tmp[3] << 16);
          *(uint2*)&vt[(size_t)(b * 16 + h) * VT_BH_STRIDE + (nloc >> 2) * 256 + dd * 4] = pv;
        }
      }
    }
  }
}

// ---------------- causal flash attention: (q-half x kv-subtile) wave split + DBUF staging (r18 best) ----------------
__global__ __launch_bounds__(256, 2) void attn_fwd(
    const u16* __restrict__ qkv,  // [B*N][3072] bf16; Q col 0, K col 1024
    const u16* __restrict__ VT,   // [B*H][512][64][4] bf16 interleaved
    u16* __restrict__ O) {        // [B*N][1024] bf16
  const int N = 2048, TD = 3072, D = 1024;
  const int bid = blockIdx.x;
  const int qp = bid >> 6, bh = bid & 63;
  const int b = bh >> 4, h = bh & 15;
  const int t = threadIdx.x, w = t >> 6, lane = t & 63;
  const int l31 = lane & 31, hi = lane >> 5;
  const int qh = w >> 1, st = w & 1;

  __shared__ alignas(16) u16 pool16[2][2][64 * 64];
  __shared__ float rsLds[2][32];
  float* poolf = (float*)&pool16[0][0][0];

  const int c1 = t, c2 = t + 256;
  const int r1 = c1 >> 3, sc1 = ((c1 & 7) ^ (r1 & 7)) * 8;
  const int r2 = c2 >> 3, sc2 = ((c2 & 7) ^ (r2 & 7)) * 8;
  const u16* kbase = qkv + (size_t)(b * N) * TD + D + h * 64;
  const u16* vbase = VT + (size_t)bh * VT_BH_STRIDE;

#define ASTAGE(buf, j0) do { \
    STG(kbase + (size_t)((j0) + r1) * TD + sc1, &pool16[buf][0][c1 * 8]); \
    STG(kbase + (size_t)((j0) + r2) * TD + sc2, &pool16[buf][0][c2 * 8]); \
    STG(vbase + (size_t)(j0) * 64 + c1 * 8, &pool16[buf][1][c1 * 8]); \
    STG(vbase + (size_t)(j0) * 64 + c2 * 8, &pool16[buf][1][c2 * 8]); } while (0)

  const float L2E = 1.44269504089f;
  const float NSH = -23.0830992f;  // -16*log2(e): p = exp2(s*L2E + NSH) = exp(s-16)

  for (int pass = 0; pass < 2; ++pass) {
    const int qt = pass ? (15 - qp) : qp;
    const int qbw = qt * 128 + qh * 64;

    bf16x8 qf[2][4];
    #pragma unroll
    for (int qs = 0; qs < 2; ++qs) {
      const u16* qp_ = qkv + ((size_t)(b * N) + qbw + qs * 32 + l31) * TD + h * 64 + hi * 8;
      #pragma unroll
      for (int c = 0; c < 4; ++c) {
        bf16x8 v = *(const bf16x8*)(qp_ + c * 16);
        #pragma unroll
        for (int j = 0; j < 8; ++j)
          v[j] = (short)f2b(b2f((u16)v[j]) * 0.125f);
        qf[qs][c] = v;
      }
    }

    f32x16 o_acc[2][2] = {};
    float psum[2] = {0.f, 0.f};
    const int jend = qt * 128 + 64;

    ASTAGE(0, 0);
    __syncthreads();

    int cur = 0;
    for (int j0 = 0; j0 <= jend; j0 += 64) {
      if (j0 + 64 <= jend) ASTAGE(cur ^ 1, j0 + 64);

      const int sb2 = j0 + st * 32;
      if (sb2 <= qbw + 63) {
        bf16x8 kf[4];
        {
          const int row = st * 32 + l31, sw = (row & 7) << 3;
          #pragma unroll
          for (int c = 0; c < 4; ++c)
            kf[c] = *(const bf16x8*)&pool16[cur][0][row * 64 + ((c * 16 + hi * 8) ^ sw)];
        }
        // vf: interleaved LDS [n>>2][64 dd][n&3]; 8 consecutive n = two uint2s (+0, +256)
        bf16x8 vf[2][2];  // [kc][dt]
        #pragma unroll
        for (int dt = 0; dt < 2; ++dt) {
          const int dd = dt * 32 + l31;
          #pragma unroll
          for (int kc = 0; kc < 2; ++kc) {
            const int nb = st * 32 + kc * 16 + hi * 8;
            union { uint2 q[2]; bf16x8 v; } u;
            u.q[0] = *(const uint2*)&pool16[cur][1][(nb >> 2) * 256 + dd * 4];
            u.q[1] = *(const uint2*)&pool16[cur][1][(nb >> 2) * 256 + 256 + dd * 4];
            vf[kc][dt] = u.v;
          }
        }

        #pragma unroll
        for (int qs = 0; qs < 2; ++qs) {
          if (qs == 0 && sb2 > qbw + 31) continue;
          const int qr = qbw + qs * 32 + l31;
          f32x16 S = {};
          __builtin_amdgcn_s_setprio(1);
          #pragma unroll
          for (int c = 0; c < 4; ++c)
            S = __builtin_amdgcn_mfma_f32_32x32x16_bf16(kf[c], qf[qs][c], S, 0, 0, 0);
          __builtin_amdgcn_s_setprio(0);
          if (sb2 + 31 > qbw + qs * 32) {
            const int kvb = sb2 + 4 * hi;
            #pragma unroll
            for (int r = 0; r < 16; ++r)
              if (kvb + (r & 3) + 8 * (r >> 2) > qr) S[r] = -1e30f;
          }
          float p[16];
          #pragma unroll
          for (int r = 0; r < 16; ++r) p[r] = EXP2F(fmaf(S[r], L2E, NSH));
          float ps = 0.f;
          #pragma unroll
          for (int r = 0; r < 16; ++r) ps += p[r];
          psum[qs] += ps;
          u32 wq[8];
          #pragma unroll
          for (int i = 0; i < 8; ++i) wq[i] = cvt_pk_bf16(p[2 * i], p[2 * i + 1]);
          permswap(wq[0], wq[2]); permswap(wq[1], wq[3]);
          permswap(wq[4], wq[6]); permswap(wq[5], wq[7]);
          union { u32 u[4]; bf16x8 v; } pa0, pa1;
          pa0.u[0] = wq[0]; pa0.u[1] = wq[1]; pa0.u[2] = wq[2]; pa0.u[3] = wq[3];
          pa1.u[0] = wq[4]; pa1.u[1] = wq[5]; pa1.u[2] = wq[6]; pa1.u[3] = wq[7];
          __builtin_amdgcn_s_setprio(1);
          #pragma unroll
          for (int dt = 0; dt < 2; ++dt) {
            o_acc[qs][dt] = __builtin_amdgcn_mfma_f32_32x32x16_bf16(pa0.v, vf[0][dt], o_acc[qs][dt], 0, 0, 0);
            o_acc[qs][dt] = __builtin_amdgcn_mfma_f32_32x32x16_bf16(pa1.v, vf[1][dt], o_acc[qs][dt], 0, 0, 0);
          }
          __builtin_amdgcn_s_setprio(0);
        }
      }
      __syncthreads();
      cur ^= 1;
    }

    float rsown[2];
    #pragma unroll
    for (int qs = 0; qs < 2; ++qs)
      rsown[qs] = psum[qs] + __shfl_xor(psum[qs], 32, 64);

    #pragma unroll
    for (int qs = 0; qs < 2; ++qs) {
      if (st != qs) {
        #pragma unroll
        for (int dt = 0; dt < 2; ++dt)
          #pragma unroll
          for (int r = 0; r < 16; ++r)
            poolf[qh * 2048 + (dt * 16 + r) * 64 + lane] = o_acc[qs][dt][r];
        rsLds[qh][l31] = rsown[qs];
      }
      __syncthreads();
      if (st == qs) {
        const float inv = 1.0f / (rsown[qs] + rsLds[qh][l31]);
        #pragma unroll
        for (int r = 0; r < 16; ++r) {
          const int qrow = (r & 3) + 8 * (r >> 2) + 4 * hi;
          const float invq = __shfl(inv, qrow, 64);
          const int q = qbw + qs * 32 + qrow;
          #pragma unroll
          for (int dt = 0; dt < 2; ++dt) {
            const float val = o_acc[qs][dt][r] + poolf[qh * 2048 + (dt * 16 + r) * 64 + lane];
            O[((size_t)(b * N) + q) * D + h * 64 + dt * 32 + l31] = f2b(val * invq);
          }
        }
      }
      __syncthreads();
    }
  }
#undef ASTAGE
}

extern "C" void kernel_launch(void* const* d_in, const int* in_sizes, int n_in,
                              void* d_out, int out_size, void* d_ws, size_t ws_size,
                              hipStream_t stream) {
  const float* x     = (const float*)d_in[0];
  // d_in[1] = causal_mask (fp32): handled structurally, unused
  const float* Wqkv  = (const float*)d_in[2];
  const float* bqkv  = (const float*)d_in[3];
  const float* Wproj = (const float*)d_in[4];
  const float* bproj = (const float*)d_in[5];
  float* out = (float*)d_out;

  const int B = 4, N = 2048, D = 1024, H = 16;
  const int BN = B * N;    // 8192
  const int TD = 3 * D;    // 3072

  char* ws = (char*)d_ws;
  u16* qkv    = (u16*)(ws);                      // 50,331,648 B
  u16* vt     = (u16*)(ws + 50331648);           // 16,777,216 B
  u16* aout   = (u16*)(ws + 67108864);           // 16,777,216 B
  u16* wqkvT  = (u16*)(ws + 83886080);           //  6,291,456 B
  u16* wprojT = (u16*)(ws + 90177536);           //  2,097,152 B
  u16* xb     = (u16*)(ws + 92274688);           // 16,777,216 B

  // 1) fused prep: x->bf16 cast + both weight transposes
  prep<<<6144, 256, 0, stream>>>(x, xb, Wqkv, wqkvT, Wproj, wprojT);
  // 2) QKV projection (r9 structure, 2D grid) + fused V-transpose into interleaved vt
  gemm_bt_bias<u16, true><<<dim3(BN / 128, TD / 128), 256, 0, stream>>>(xb, wqkvT, bqkv, qkv, BN, TD, D, vt);
  // 3) causal flash attention (r18 best: 128-row paired q-tiles, 8 qp x 64 bh)
  attn_fwd<<<512, 256, 0, stream>>>(qkv, vt, aout);
  // 4) output projection (fp32 out + bias, 2D grid)
  gemm_bt_bias<float, false><<<dim3(BN / 128, D / 128), 256, 0, stream>>>(aout, wprojT, bproj, out, BN, D, D, nullptr);
}

// Round 22
// 177.979 us; speedup vs baseline: 1.1284x; 1.0077x over previous
//
#include <hip/hip_runtime.h>
#include <hip/hip_bf16.h>

typedef unsigned short u16;
typedef unsigned int u32;
typedef __attribute__((ext_vector_type(8))) short bf16x8;
typedef __attribute__((ext_vector_type(4))) float f32x4;
typedef __attribute__((ext_vector_type(16))) float f32x16;

#define AS1(p) ((const __attribute__((address_space(1))) void*)(p))
#define AS3(p) ((__attribute__((address_space(3))) void*)(p))
#define STG(src, dst) __builtin_amdgcn_global_load_lds(AS1(src), AS3(dst), 16, 0, 0)

#if __has_builtin(__builtin_amdgcn_exp2f)
#define EXP2F(x) __builtin_amdgcn_exp2f(x)
#else
#define EXP2F(x) exp2f(x)
#endif

// vt interleaved layout: [bh][n>>2][64 dd][n&3]; per-bh stride = 2048*64 = 131072 u16.
#define VT_BH_STRIDE 131072

static __device__ __forceinline__ float b2f(u16 u) {
  union { unsigned int i; float f; } v; v.i = ((unsigned int)u) << 16; return v.f;
}
static __device__ __forceinline__ u16 f2b(float f) {
  union { float f; unsigned int i; } v; v.f = f;
  unsigned int r = v.i + 0x7FFFu + ((v.i >> 16) & 1u);
  return (u16)(r >> 16);
}
static __device__ __forceinline__ u32 cvt_pk_bf16(float lo, float hi) {
  u32 r;
  asm("v_cvt_pk_bf16_f32 %0, %1, %2" : "=v"(r) : "v"(lo), "v"(hi));
  return r;
}
static __device__ __forceinline__ void permswap(u32& a, u32& b) {
  asm("v_permlane32_swap_b32 %0, %1" : "+v"(a), "+v"(b));
}

// ---------------- fused prep: x cast (blocks 0..2047) + Wqkv^T (2048..5119) + Wproj^T (5120..6143) ----------------
__global__ __launch_bounds__(256) void prep(const float* __restrict__ x, u16* __restrict__ xb,
                                            const float* __restrict__ Wqkv, u16* __restrict__ wqkvT,
                                            const float* __restrict__ Wproj, u16* __restrict__ wprojT) {
  __shared__ float tile[32][33];
  const int bid = blockIdx.x, t = threadIdx.x;
  if (bid < 2048) {
    const int n8 = 8192 * 1024 / 8;
    for (int i = bid * 256 + t; i < n8; i += 2048 * 256) {
      const float4* s = (const float4*)(x + (size_t)i * 8);
      float4 a = s[0], b = s[1];
      bf16x8 o;
      o[0] = (short)f2b(a.x); o[1] = (short)f2b(a.y); o[2] = (short)f2b(a.z); o[3] = (short)f2b(a.w);
      o[4] = (short)f2b(b.x); o[5] = (short)f2b(b.y); o[6] = (short)f2b(b.z); o[7] = (short)f2b(b.w);
      *(bf16x8*)(xb + (size_t)i * 8) = o;
    }
  } else {
    const float* src; u16* dst; int R, C, cx, ry;
    if (bid < 5120) { const int l = bid - 2048; src = Wqkv; dst = wqkvT; R = 1024; C = 3072; cx = l % 96; ry = l / 96; }
    else            { const int l = bid - 5120; src = Wproj; dst = wprojT; R = 1024; C = 1024; cx = l & 31; ry = l >> 5; }
    const int c0 = cx * 32, r0 = ry * 32;
    const int tx = t & 31, ty = t >> 5;
    for (int i = ty; i < 32; i += 8) tile[i][tx] = src[(size_t)(r0 + i) * C + c0 + tx];
    __syncthreads();
    for (int i = ty; i < 32; i += 8) dst[(size_t)(c0 + i) * R + r0 + tx] = f2b(tile[tx][i]);
  }
}

// ---------------- 256x256 / BK=64 / 8-wave 8-PHASE bf16 GEMM, CORRECT swizzle (attn-proven) ----------------
// r14 schedule verbatim; swizzle replaced by the conflict-free involution used in attn:
//   read u16 idx = row*64 + (col ^ ((row&7)<<3)); staging keeps linear LDS dest with
//   pre-swizzled source col ((c&7)^(r&7))*8  (rule #21: same involution both sides).
// Counted vmcnt(2) only at phases 4/8. Optional WVT fused V-transpose epilogue.
template <bool WVT>
__global__ __launch_bounds__(512, 1) void gemm8p(
    const u16* __restrict__ A,      // [M][K] bf16
    const u16* __restrict__ BT,     // [N][K] bf16 (K contiguous)
    const float* __restrict__ bias, // [N] fp32
    u16* __restrict__ C,            // [M][N] bf16
    int M, int N, int K, int nn,
    u16* __restrict__ vt) {
  __shared__ alignas(16) u16 As[2][2][128 * 64];
  __shared__ alignas(16) u16 Bs[2][2][128 * 64];

  const int nwg = gridDim.x, cpx = nwg >> 3, id0 = blockIdx.x;
  const int swz = (id0 & 7) * cpx + (id0 >> 3);
  const int mi = swz / nn, ni = swz % nn;
  const int m0 = mi * 256, n0 = ni * 256;

  const int t = threadIdx.x;             // 0..511
  const int wid = t >> 6, lane = t & 63;
  const int wr = wid >> 2, wc = wid & 3; // 2M x 4N waves; wave C = 128x64
  const int rlo = lane & 15, g = lane >> 4;

  // staging: chunks ca=t (rows 0..63), cb=t+512 (rows 64..127); source pre-swizzled
  const int ca = t, cb = t + 512;
  const int ra = ca >> 3, sca = ((ca & 7) ^ (ra & 7)) * 8;
  const int rb = cb >> 3, scb = ((cb & 7) ^ (rb & 7)) * 8;
  const u16* aP[2][2];
  const u16* bP[2][2];
  #pragma unroll
  for (int h = 0; h < 2; ++h) {
    aP[h][0] = A + (size_t)(m0 + h * 128 + ra) * K + sca;
    aP[h][1] = A + (size_t)(m0 + h * 128 + rb) * K + scb;
    bP[h][0] = BT + (size_t)(n0 + h * 128 + ra) * K + sca;
    bP[h][1] = BT + (size_t)(n0 + h * 128 + rb) * K + scb;
  }

  f32x4 acc[8][4] = {};
  bf16x8 a[4][2], b[2][2];
  const int NT = K >> 6;

#define BAR() __builtin_amdgcn_s_barrier()
#define VM2() asm volatile("s_waitcnt vmcnt(2)" ::: "memory")
#define VM0() asm volatile("s_waitcnt vmcnt(0)" ::: "memory")
#define STAGE_A(h, jt) do { if ((jt) < NT) { const size_t ko_ = (size_t)(jt) * 64; \
    STG(aP[h][0] + ko_, &As[(jt) & 1][h][t * 8]); \
    STG(aP[h][1] + ko_, &As[(jt) & 1][h][(t + 512) * 8]); } } while (0)
#define STAGE_B(h, jt) do { if ((jt) < NT) { const size_t ko_ = (size_t)(jt) * 64; \
    STG(bP[h][0] + ko_, &Bs[(jt) & 1][h][t * 8]); \
    STG(bP[h][1] + ko_, &Bs[(jt) & 1][h][(t + 512) * 8]); } } while (0)
#define RDA(buf, mh) _Pragma("unroll") for (int fr = 0; fr < 4; ++fr) \
    _Pragma("unroll") for (int kc = 0; kc < 2; ++kc) { \
      const int r_ = (mh) * 64 + fr * 16 + rlo; \
      a[fr][kc] = *(const bf16x8*)&As[buf][wr][r_ * 64 + ((kc * 32 + g * 8) ^ ((r_ & 7) << 3))]; }
#define RDB(buf, nh) _Pragma("unroll") for (int fn = 0; fn < 2; ++fn) \
    _Pragma("unroll") for (int kc = 0; kc < 2; ++kc) { \
      const int r_ = (wc & 1) * 64 + (nh) * 32 + fn * 16 + rlo; \
      b[fn][kc] = *(const bf16x8*)&Bs[buf][wc >> 1][r_ * 64 + ((kc * 32 + g * 8) ^ ((r_ & 7) << 3))]; }
#define MM(mh, nh) __builtin_amdgcn_s_setprio(1); \
    _Pragma("unroll") for (int fr = 0; fr < 4; ++fr) \
      _Pragma("unroll") for (int fn = 0; fn < 2; ++fn) { \
        f32x4 v_ = acc[(mh) * 4 + fr][(nh) * 2 + fn]; \
        v_ = __builtin_amdgcn_mfma_f32_16x16x32_bf16(a[fr][0], b[fn][0], v_, 0, 0, 0); \
        v_ = __builtin_amdgcn_mfma_f32_16x16x32_bf16(a[fr][1], b[fn][1], v_, 0, 0, 0); \
        acc[(mh) * 4 + fr][(nh) * 2 + fn] = v_; } \
    __builtin_amdgcn_s_setprio(0)

  // prologue: K-tile 0 (4 halves) + A0(1); gate K-tile 0 (allow A0(1) in flight)
  STAGE_A(0, 0); STAGE_A(1, 0); STAGE_B(0, 0); STAGE_B(1, 0); STAGE_A(0, 1);
  VM2(); BAR();

  const int NI = NT >> 1;
  #pragma unroll 1
  for (int it = 0; it < NI; ++it) {
    const int kt1 = 2 * it + 1;
    RDA(0, 0) RDB(0, 0)
    STAGE_A(1, kt1);
    BAR(); MM(0, 0); BAR();
    RDB(0, 1)
    STAGE_B(0, kt1);
    BAR(); MM(0, 1); BAR();
    RDA(0, 1)
    STAGE_B(1, kt1);
    BAR(); MM(1, 1); BAR();
    RDB(0, 0)
    STAGE_A(0, kt1 + 1);
    if (kt1 + 1 < NT) { VM2(); } else { VM0(); }
    BAR(); MM(1, 0); BAR();
    RDA(1, 0) RDB(1, 0)
    STAGE_A(1, kt1 + 1);
    BAR(); MM(0, 0); BAR();
    RDB(1, 1)
    STAGE_B(0, kt1 + 1);
    BAR(); MM(0, 1); BAR();
    RDA(1, 1)
    STAGE_B(1, kt1 + 1);
    BAR(); MM(1, 1); BAR();
    RDB(1, 0)
    STAGE_A(0, kt1 + 2);
    if (kt1 + 1 < NT) { if (kt1 + 2 < NT) { VM2(); } else { VM0(); } }
    BAR(); MM(1, 0); BAR();
  }
#undef BAR
#undef VM2
#undef VM0
#undef STAGE_A
#undef STAGE_B
#undef RDA
#undef RDB
#undef MM

  // epilogue: bias + store (+ optional fused V-transpose into interleaved vt)
  #pragma unroll
  for (int nr = 0; nr < 4; ++nr) {
    const int col = n0 + wc * 64 + nr * 16 + rlo;
    const float bv = bias[col];
    #pragma unroll
    for (int mr = 0; mr < 8; ++mr) {
      const int row = m0 + wr * 128 + mr * 16 + g * 4;
      u16 tmp[4];
      #pragma unroll
      for (int i = 0; i < 4; ++i) {
        const u16 hv = f2b(acc[mr][nr][i] + bv);
        C[(size_t)(row + i) * N + col] = hv;
        tmp[i] = hv;
      }
      if constexpr (WVT) {
        if (col >= 2048) {
          const int cv = col - 2048;
          const int h = cv >> 6, dd = cv & 63;
          const int b = row >> 11, nloc = row & 2047;  // 256-row tiles never cross batch
          uint2 pv;
          pv.x = (u32)tmp[0] | ((u32)tmp[1] << 16);
          pv.y = (u32)tmp[2] | ((u32)tmp[3] << 16);
          *(uint2*)&vt[(size_t)(b * 16 + h) * VT_BH_STRIDE + (nloc >> 2) * 256 + dd * 4] = pv;
        }
      }
    }
  }
}

// ---------------- m97-structure bf16 GEMM (r9 measured best; used for proj) ----------------
template <typename OutT, bool WVT>
__global__ __launch_bounds__(256) void gemm_bt_bias(
    const u16* __restrict__ A,     // [M][K] bf16
    const u16* __restrict__ BT,    // [N][K] bf16 (K contiguous)
    const float* __restrict__ bias,// [N] fp32
    OutT* __restrict__ C,          // [M][N]
    int M, int N, int K,
    u16* __restrict__ vt) {
  __shared__ alignas(16) u16 Als[128 * 32];
  __shared__ alignas(16) u16 Bls[128 * 32];
  const int m0 = blockIdx.x * 128, n0 = blockIdx.y * 128;
  const int t = threadIdx.x;
  const int w = t >> 6, lane = t & 63;
  const int wr = w >> 1, wc = w & 1;
  const int rlo = lane & 15, g = lane >> 4;

  f32x4 acc[4][4] = {};

  const int r0 = t >> 2;
  const int c0 = (t & 3) << 3;
  const u16* aSrc = A + (size_t)(m0 + r0) * K + c0;
  const u16* bSrc = BT + (size_t)(n0 + r0) * K + c0;

  for (int k0 = 0; k0 < K; k0 += 32) {
    __builtin_amdgcn_global_load_lds(AS1(aSrc + k0), AS3(&Als[t * 8]), 16, 0, 0);
    __builtin_amdgcn_global_load_lds(AS1(aSrc + (size_t)64 * K + k0), AS3(&Als[(t + 256) * 8]), 16, 0, 0);
    __builtin_amdgcn_global_load_lds(AS1(bSrc + k0), AS3(&Bls[t * 8]), 16, 0, 0);
    __builtin_amdgcn_global_load_lds(AS1(bSrc + (size_t)64 * K + k0), AS3(&Bls[(t + 256) * 8]), 16, 0, 0);
    __syncthreads();

    bf16x8 a[4], b[4];
    #pragma unroll
    for (int m = 0; m < 4; ++m)
      a[m] = *(const bf16x8*)&Als[(wr * 64 + m * 16 + rlo) * 32 + g * 8];
    #pragma unroll
    for (int n = 0; n < 4; ++n)
      b[n] = *(const bf16x8*)&Bls[(wc * 64 + n * 16 + rlo) * 32 + g * 8];
    #pragma unroll
    for (int m = 0; m < 4; ++m)
      #pragma unroll
      for (int n = 0; n < 4; ++n)
        acc[m][n] = __builtin_amdgcn_mfma_f32_16x16x32_bf16(a[m], b[n], acc[m][n], 0, 0, 0);
    __syncthreads();
  }

  #pragma unroll
  for (int n = 0; n < 4; ++n) {
    const int col = n0 + wc * 64 + n * 16 + rlo;
    const float bv = bias[col];
    #pragma unroll
    for (int m = 0; m < 4; ++m) {
      const int row = m0 + wr * 64 + m * 16 + g * 4;
      #pragma unroll
      for (int i = 0; i < 4; ++i) {
        float r = acc[m][n][i] + bv;
        if constexpr (sizeof(OutT) == 2)
          C[(size_t)(row + i) * N + col] = (OutT)f2b(r);
        else
          C[(size_t)(row + i) * N + col] = (OutT)r;
      }
    }
  }
}

// ---------------- causal flash attention: (q-half x kv-subtile) wave split + DBUF staging (r18 best) ----------------
__global__ __launch_bounds__(256, 2) void attn_fwd(
    const u16* __restrict__ qkv,  // [B*N][3072] bf16; Q col 0, K col 1024
    const u16* __restrict__ VT,   // [B*H][512][64][4] bf16 interleaved
    u16* __restrict__ O) {        // [B*N][1024] bf16
  const int N = 2048, TD = 3072, D = 1024;
  const int bid = blockIdx.x;
  const int qp = bid >> 6, bh = bid & 63;
  const int b = bh >> 4, h = bh & 15;
  const int t = threadIdx.x, w = t >> 6, lane = t & 63;
  const int l31 = lane & 31, hi = lane >> 5;
  const int qh = w >> 1, st = w & 1;

  __shared__ alignas(16) u16 pool16[2][2][64 * 64];
  __shared__ float rsLds[2][32];
  float* poolf = (float*)&pool16[0][0][0];

  const int c1 = t, c2 = t + 256;
  const int r1 = c1 >> 3, sc1 = ((c1 & 7) ^ (r1 & 7)) * 8;
  const int r2 = c2 >> 3, sc2 = ((c2 & 7) ^ (r2 & 7)) * 8;
  const u16* kbase = qkv + (size_t)(b * N) * TD + D + h * 64;
  const u16* vbase = VT + (size_t)bh * VT_BH_STRIDE;

#define ASTAGE(buf, j0) do { \
    STG(kbase + (size_t)((j0) + r1) * TD + sc1, &pool16[buf][0][c1 * 8]); \
    STG(kbase + (size_t)((j0) + r2) * TD + sc2, &pool16[buf][0][c2 * 8]); \
    STG(vbase + (size_t)(j0) * 64 + c1 * 8, &pool16[buf][1][c1 * 8]); \
    STG(vbase + (size_t)(j0) * 64 + c2 * 8, &pool16[buf][1][c2 * 8]); } while (0)

  const float L2E = 1.44269504089f;
  const float NSH = -23.0830992f;  // -16*log2(e): p = exp2(s*L2E + NSH) = exp(s-16)

  for (int pass = 0; pass < 2; ++pass) {
    const int qt = pass ? (15 - qp) : qp;
    const int qbw = qt * 128 + qh * 64;

    bf16x8 qf[2][4];
    #pragma unroll
    for (int qs = 0; qs < 2; ++qs) {
      const u16* qp_ = qkv + ((size_t)(b * N) + qbw + qs * 32 + l31) * TD + h * 64 + hi * 8;
      #pragma unroll
      for (int c = 0; c < 4; ++c) {
        bf16x8 v = *(const bf16x8*)(qp_ + c * 16);
        #pragma unroll
        for (int j = 0; j < 8; ++j)
          v[j] = (short)f2b(b2f((u16)v[j]) * 0.125f);
        qf[qs][c] = v;
      }
    }

    f32x16 o_acc[2][2] = {};
    float psum[2] = {0.f, 0.f};
    const int jend = qt * 128 + 64;

    ASTAGE(0, 0);
    __syncthreads();

    int cur = 0;
    for (int j0 = 0; j0 <= jend; j0 += 64) {
      if (j0 + 64 <= jend) ASTAGE(cur ^ 1, j0 + 64);

      const int sb2 = j0 + st * 32;
      if (sb2 <= qbw + 63) {
        bf16x8 kf[4];
        {
          const int row = st * 32 + l31, sw = (row & 7) << 3;
          #pragma unroll
          for (int c = 0; c < 4; ++c)
            kf[c] = *(const bf16x8*)&pool16[cur][0][row * 64 + ((c * 16 + hi * 8) ^ sw)];
        }
        bf16x8 vf[2][2];  // [kc][dt]
        #pragma unroll
        for (int dt = 0; dt < 2; ++dt) {
          const int dd = dt * 32 + l31;
          #pragma unroll
          for (int kc = 0; kc < 2; ++kc) {
            const int nb = st * 32 + kc * 16 + hi * 8;
            union { uint2 q[2]; bf16x8 v; } u;
            u.q[0] = *(const uint2*)&pool16[cur][1][(nb >> 2) * 256 + dd * 4];
            u.q[1] = *(const uint2*)&pool16[cur][1][(nb >> 2) * 256 + 256 + dd * 4];
            vf[kc][dt] = u.v;
          }
        }

        #pragma unroll
        for (int qs = 0; qs < 2; ++qs) {
          if (qs == 0 && sb2 > qbw + 31) continue;
          const int qr = qbw + qs * 32 + l31;
          f32x16 S = {};
          __builtin_amdgcn_s_setprio(1);
          #pragma unroll
          for (int c = 0; c < 4; ++c)
            S = __builtin_amdgcn_mfma_f32_32x32x16_bf16(kf[c], qf[qs][c], S, 0, 0, 0);
          __builtin_amdgcn_s_setprio(0);
          if (sb2 + 31 > qbw + qs * 32) {
            const int kvb = sb2 + 4 * hi;
            #pragma unroll
            for (int r = 0; r < 16; ++r)
              if (kvb + (r & 3) + 8 * (r >> 2) > qr) S[r] = -1e30f;
          }
          float p[16];
          #pragma unroll
          for (int r = 0; r < 16; ++r) p[r] = EXP2F(fmaf(S[r], L2E, NSH));
          float ps = 0.f;
          #pragma unroll
          for (int r = 0; r < 16; ++r) ps += p[r];
          psum[qs] += ps;
          u32 wq[8];
          #pragma unroll
          for (int i = 0; i < 8; ++i) wq[i] = cvt_pk_bf16(p[2 * i], p[2 * i + 1]);
          permswap(wq[0], wq[2]); permswap(wq[1], wq[3]);
          permswap(wq[4], wq[6]); permswap(wq[5], wq[7]);
          union { u32 u[4]; bf16x8 v; } pa0, pa1;
          pa0.u[0] = wq[0]; pa0.u[1] = wq[1]; pa0.u[2] = wq[2]; pa0.u[3] = wq[3];
          pa1.u[0] = wq[4]; pa1.u[1] = wq[5]; pa1.u[2] = wq[6]; pa1.u[3] = wq[7];
          __builtin_amdgcn_s_setprio(1);
          #pragma unroll
          for (int dt = 0; dt < 2; ++dt) {
            o_acc[qs][dt] = __builtin_amdgcn_mfma_f32_32x32x16_bf16(pa0.v, vf[0][dt], o_acc[qs][dt], 0, 0, 0);
            o_acc[qs][dt] = __builtin_amdgcn_mfma_f32_32x32x16_bf16(pa1.v, vf[1][dt], o_acc[qs][dt], 0, 0, 0);
          }
          __builtin_amdgcn_s_setprio(0);
        }
      }
      __syncthreads();
      cur ^= 1;
    }

    float rsown[2];
    #pragma unroll
    for (int qs = 0; qs < 2; ++qs)
      rsown[qs] = psum[qs] + __shfl_xor(psum[qs], 32, 64);

    #pragma unroll
    for (int qs = 0; qs < 2; ++qs) {
      if (st != qs) {
        #pragma unroll
        for (int dt = 0; dt < 2; ++dt)
          #pragma unroll
          for (int r = 0; r < 16; ++r)
            poolf[qh * 2048 + (dt * 16 + r) * 64 + lane] = o_acc[qs][dt][r];
        rsLds[qh][l31] = rsown[qs];
      }
      __syncthreads();
      if (st == qs) {
        const float inv = 1.0f / (rsown[qs] + rsLds[qh][l31]);
        #pragma unroll
        for (int r = 0; r < 16; ++r) {
          const int qrow = (r & 3) + 8 * (r >> 2) + 4 * hi;
          const float invq = __shfl(inv, qrow, 64);
          const int q = qbw + qs * 32 + qrow;
          #pragma unroll
          for (int dt = 0; dt < 2; ++dt) {
            const float val = o_acc[qs][dt][r] + poolf[qh * 2048 + (dt * 16 + r) * 64 + lane];
            O[((size_t)(b * N) + q) * D + h * 64 + dt * 32 + l31] = f2b(val * invq);
          }
        }
      }
      __syncthreads();
    }
  }
#undef ASTAGE
}

extern "C" void kernel_launch(void* const* d_in, const int* in_sizes, int n_in,
                              void* d_out, int out_size, void* d_ws, size_t ws_size,
                              hipStream_t stream) {
  const float* x     = (const float*)d_in[0];
  // d_in[1] = causal_mask (fp32): handled structurally, unused
  const float* Wqkv  = (const float*)d_in[2];
  const float* bqkv  = (const float*)d_in[3];
  const float* Wproj = (const float*)d_in[4];
  const float* bproj = (const float*)d_in[5];
  float* out = (float*)d_out;

  const int B = 4, N = 2048, D = 1024, H = 16;
  const int BN = B * N;    // 8192
  const int TD = 3 * D;    // 3072

  char* ws = (char*)d_ws;
  u16* qkv    = (u16*)(ws);                      // 50,331,648 B
  u16* vt     = (u16*)(ws + 50331648);           // 16,777,216 B
  u16* aout   = (u16*)(ws + 67108864);           // 16,777,216 B
  u16* wqkvT  = (u16*)(ws + 83886080);           //  6,291,456 B
  u16* wprojT = (u16*)(ws + 90177536);           //  2,097,152 B
  u16* xb     = (u16*)(ws + 92274688);           // 16,777,216 B

  // 1) fused prep: x->bf16 cast + both weight transposes
  prep<<<6144, 256, 0, stream>>>(x, xb, Wqkv, wqkvT, Wproj, wprojT);
  // 2) QKV projection: 8-phase 256x256 w/ corrected swizzle + fused V-transpose
  gemm8p<true><<<384, 512, 0, stream>>>(xb, wqkvT, bqkv, qkv, BN, TD, D, 12, vt);
  // 3) causal flash attention (r18 best: 128-row paired q-tiles, 8 qp x 64 bh)
  attn_fwd<<<512, 256, 0, stream>>>(qkv, vt, aout);
  // 4) output projection (r9 m97 structure, fp32 out + bias)
  gemm_bt_bias<float, false><<<dim3(BN / 128, D / 128), 256, 0, stream>>>(aout, wprojT, bproj, out, BN, D, D, nullptr);
}